// Round 4
// baseline (274.264 us; speedup 1.0000x reference)
//
#include <hip/hip_runtime.h>
#include <hip/hip_bf16.h>

// GraphAttention2: N=6144, F=128, C=64, H=4. A ~1% sparse + self loops.
// R4: split the fused agg into (scan -> CSR) + (CSR -> softmax-aggregate) so
// the 151 MB A-stream saturates HBM without barrier-serialized softmax/gather
// phases starving the memory pipe. agg2 is small and L2-resident.

#define N_NODES 6144
#define F_DIM   128
#define C_DIM   64
#define H_HEADS 4
#define HC      (H_HEADS * C_DIM)   // 256
#define MAXK    256   // max neighbors/row; E[K]=61, max ~100 across 6144 rows

// ---------------------------------------------------------------------------
// Kernel 1: per-head projections, fused layouts:
//   featsT / feats2T : [N][H][C]   (1 KB per node)
//   attsT / attnT    : [N][H]      (16 B per node)
// Grid: (N/64, H*2). Block 256, 64x64 tile, K=128 LDS-resident.
// ---------------------------------------------------------------------------
__global__ __launch_bounds__(256) void proj_kernel(
    const float* __restrict__ X,
    const float* __restrict__ W1, const float* __restrict__ W2,
    const float* __restrict__ a_self, const float* __restrict__ a_neigh,
    float* __restrict__ featsT, float* __restrict__ feats2T,
    float* __restrict__ attsT, float* __restrict__ attnT)
{
    const int rt    = blockIdx.x;
    const int z     = blockIdx.y;
    const int h     = z >> 1;
    const int which = z & 1;

    const float* W    = (which ? W2 : W1) + h * F_DIM * C_DIM;
    float*       outp = which ? feats2T : featsT;

    __shared__ float  Xs[64][132];    // [r][k], +4 pad
    __shared__ float4 Ws4[128][17];   // [k][c/4], +1 float4 pad

    const int tid = threadIdx.x;

    {
        const float4* Xg = (const float4*)(X + (size_t)rt * 64 * F_DIM);
        for (int u = tid; u < 64 * 32; u += 256) {
            const int r = u >> 5, q = u & 31;
            *(float4*)&Xs[r][4 * q] = Xg[u];
        }
        const float4* Wg = (const float4*)W;
        for (int u = tid; u < 128 * 16; u += 256) {
            Ws4[u >> 4][u & 15] = Wg[u];
        }
    }
    __syncthreads();

    const int tx = tid & 15;   // cols 4*tx..4*tx+3
    const int ty = tid >> 4;   // rows 4*ty..4*ty+3

    float acc[4][4] = {};
    for (int k = 0; k < 128; k += 4) {
        const float4 b0 = Ws4[k + 0][tx];
        const float4 b1 = Ws4[k + 1][tx];
        const float4 b2 = Ws4[k + 2][tx];
        const float4 b3 = Ws4[k + 3][tx];
        #pragma unroll
        for (int i = 0; i < 4; ++i) {
            const float4 x = *(const float4*)&Xs[4 * ty + i][k];
            acc[i][0] += x.x * b0.x + x.y * b1.x + x.z * b2.x + x.w * b3.x;
            acc[i][1] += x.x * b0.y + x.y * b1.y + x.z * b2.y + x.w * b3.y;
            acc[i][2] += x.x * b0.z + x.y * b1.z + x.z * b2.z + x.w * b3.z;
            acc[i][3] += x.x * b0.w + x.y * b1.w + x.z * b2.w + x.w * b3.w;
        }
    }

    __syncthreads();           // Xs no longer needed; reuse as C-tile scratch
    float* Ct = &Xs[0][0];     // viewed as [64][65]

    #pragma unroll
    for (int i = 0; i < 4; ++i) {
        const int r    = 4 * ty + i;
        const int node = rt * 64 + r;
        *(float4*)&outp[(size_t)node * HC + h * C_DIM + 4 * tx] =
            make_float4(acc[i][0], acc[i][1], acc[i][2], acc[i][3]);
        if (which == 0) {
            Ct[r * 65 + 4 * tx + 0] = acc[i][0];
            Ct[r * 65 + 4 * tx + 1] = acc[i][1];
            Ct[r * 65 + 4 * tx + 2] = acc[i][2];
            Ct[r * 65 + 4 * tx + 3] = acc[i][3];
        }
    }

    if (which == 0) {
        __syncthreads();
        if (tid < 64) {
            const float* as_ = a_self  + h * C_DIM;
            const float* an_ = a_neigh + h * C_DIM;
            float s = 0.f, n = 0.f;
            #pragma unroll 8
            for (int c = 0; c < C_DIM; ++c) {
                const float v = Ct[tid * 65 + c];
                s += v * as_[c];
                n += v * an_[c];
            }
            const int node = rt * 64 + tid;
            attsT[node * H_HEADS + h] = s;
            attnT[node * H_HEADS + h] = n;
        }
    }
}

// ---------------------------------------------------------------------------
// Kernel 2: A-row scan -> CSR. One block (256) per row. Pure HBM stream:
// 6 float4 loads issued back-to-back per lane (96 B in flight), then compact.
// ---------------------------------------------------------------------------
__global__ __launch_bounds__(256) void scan_kernel(
    const float* __restrict__ A,
    int* __restrict__ nbr, int* __restrict__ nbr_cnt)
{
    const int i   = blockIdx.x;
    const int tid = threadIdx.x;

    __shared__ int idxs[MAXK];
    __shared__ int cnt;
    if (tid == 0) cnt = 0;
    __syncthreads();

    const float4* Arow = (const float4*)(A + (size_t)i * N_NODES);
    // N/4 = 1536 float4 / 256 threads = exactly 6 per lane; issue all first.
    const float4 v0 = Arow[tid];
    const float4 v1 = Arow[tid + 256];
    const float4 v2 = Arow[tid + 512];
    const float4 v3 = Arow[tid + 768];
    const float4 v4 = Arow[tid + 1024];
    const float4 v5 = Arow[tid + 1280];

    #define SCAN4(v, base)                                                        \
        if ((v).x > 0.5f) { int p = atomicAdd(&cnt, 1); if (p < MAXK) idxs[p] = (base) + 0; } \
        if ((v).y > 0.5f) { int p = atomicAdd(&cnt, 1); if (p < MAXK) idxs[p] = (base) + 1; } \
        if ((v).z > 0.5f) { int p = atomicAdd(&cnt, 1); if (p < MAXK) idxs[p] = (base) + 2; } \
        if ((v).w > 0.5f) { int p = atomicAdd(&cnt, 1); if (p < MAXK) idxs[p] = (base) + 3; }
    SCAN4(v0, 4 * tid)
    SCAN4(v1, 4 * (tid + 256))
    SCAN4(v2, 4 * (tid + 512))
    SCAN4(v3, 4 * (tid + 768))
    SCAN4(v4, 4 * (tid + 1024))
    SCAN4(v5, 4 * (tid + 1280))
    #undef SCAN4
    __syncthreads();

    const int K = min(cnt, MAXK);
    if (tid == 0) nbr_cnt[i] = K;
    for (int p = tid; p < K; p += 256) nbr[i * MAXK + p] = idxs[p];
}

// ---------------------------------------------------------------------------
// Kernel 3: CSR -> softmax-aggregate. One block (256) per node. Small LDS
// (~5.5 KB) -> 8 blocks/CU; everything it touches is L2/LIC-resident.
// ---------------------------------------------------------------------------
__global__ __launch_bounds__(256) void agg2_kernel(
    const int* __restrict__ nbr, const int* __restrict__ nbr_cnt,
    const float* __restrict__ featsT, const float* __restrict__ feats2T,
    const float* __restrict__ attsT, const float* __restrict__ attnT,
    const float* __restrict__ bias,
    float* __restrict__ out)
{
    const int i   = blockIdx.x;
    const int tid = threadIdx.x;

    __shared__ int   idxs[MAXK];
    __shared__ float ews[H_HEADS][MAXK];
    __shared__ float mh[H_HEADS], Zh[H_HEADS], si[H_HEADS];
    __shared__ float nodebuf[256];

    const int K = nbr_cnt[i];
    if (tid < H_HEADS) si[tid] = attsT[i * H_HEADS + tid];
    if (tid < K) idxs[tid] = nbr[i * MAXK + tid];   // K <= 100 << 256
    __syncthreads();

    // Logits: one float4 attnT load gives all 4 heads
    const float4* an4 = (const float4*)attnT;
    for (int k = tid; k < K; k += 256) {
        const float4 an = an4[idxs[k]];
        float l;
        l = si[0] + an.x; ews[0][k] = (l > 0.f) ? l : 0.2f * l;
        l = si[1] + an.y; ews[1][k] = (l > 0.f) ? l : 0.2f * l;
        l = si[2] + an.z; ews[2][k] = (l > 0.f) ? l : 0.2f * l;
        l = si[3] + an.w; ews[3][k] = (l > 0.f) ? l : 0.2f * l;
    }
    __syncthreads();

    const int w    = tid >> 6;   // wave id == head id
    const int lane = tid & 63;

    // Per-head max
    {
        float m = -1e30f;
        for (int k = lane; k < K; k += 64) m = fmaxf(m, ews[w][k]);
        #pragma unroll
        for (int off = 32; off > 0; off >>= 1) m = fmaxf(m, __shfl_down(m, off));
        if (lane == 0) mh[w] = m;
    }
    __syncthreads();

    // exp + per-head sum
    {
        const float m = mh[w];
        float zsum = 0.f;
        for (int k = lane; k < K; k += 64) {
            const float e = __expf(ews[w][k] - m);
            ews[w][k] = e;
            zsum += e;
        }
        #pragma unroll
        for (int off = 32; off > 0; off >>= 1) zsum += __shfl_down(zsum, off);
        if (lane == 0) Zh[w] = zsum;
    }
    __syncthreads();

    // Gather-accumulate, 8 independent loads in flight per chunk.
    // Per wave all lanes share j -> one coalesced 256 B load per gather.
    const int h = w, c = lane;
    const float* fh = featsT + h * C_DIM + c;   // stride HC=256 floats/node
    float acc = 0.f;
    int k = 0;
    for (; k + 8 <= K; k += 8) {
        const int4   j0 = *(const int4*)&idxs[k];
        const int4   j1 = *(const int4*)&idxs[k + 4];
        const float4 w0 = *(const float4*)&ews[h][k];
        const float4 w1 = *(const float4*)&ews[h][k + 4];
        const float f0 = fh[(size_t)j0.x * HC];
        const float f1 = fh[(size_t)j0.y * HC];
        const float f2 = fh[(size_t)j0.z * HC];
        const float f3 = fh[(size_t)j0.w * HC];
        const float f4 = fh[(size_t)j1.x * HC];
        const float f5 = fh[(size_t)j1.y * HC];
        const float f6 = fh[(size_t)j1.z * HC];
        const float f7 = fh[(size_t)j1.w * HC];
        acc += w0.x * f0 + w0.y * f1 + w0.z * f2 + w0.w * f3
             + w1.x * f4 + w1.y * f5 + w1.z * f6 + w1.w * f7;
    }
    for (; k < K; ++k) acc += ews[h][k] * fh[(size_t)idxs[k] * HC];

    const float node = acc / Zh[h]
                     + feats2T[(size_t)i * HC + tid]
                     + bias[tid];                 // bias[h][c] == bias[tid]
    nodebuf[tid] = node;
    __syncthreads();

    // Head mean + relu
    if (tid < 64) {
        const float s = nodebuf[tid] + nodebuf[64 + tid] + nodebuf[128 + tid] + nodebuf[192 + tid];
        out[(size_t)i * C_DIM + tid] = fmaxf(0.25f * s, 0.f);
    }
}

extern "C" void kernel_launch(void* const* d_in, const int* in_sizes, int n_in,
                              void* d_out, int out_size, void* d_ws, size_t ws_size,
                              hipStream_t stream) {
    const float* X       = (const float*)d_in[0];
    const float* A       = (const float*)d_in[1];
    const float* W1      = (const float*)d_in[2];
    const float* W2      = (const float*)d_in[3];
    const float* a_self  = (const float*)d_in[4];
    const float* a_neigh = (const float*)d_in[5];
    const float* bias    = (const float*)d_in[6];
    float* out = (float*)d_out;

    // Workspace layout (floats/ints): featsT | feats2T | attsT | attnT | nbr | cnt
    float* ws      = (float*)d_ws;
    float* featsT  = ws;                                    // N*H*C
    float* feats2T = featsT  + (size_t)N_NODES * HC;
    float* attsT   = feats2T + (size_t)N_NODES * HC;        // N*H
    float* attnT   = attsT   + (size_t)N_NODES * H_HEADS;
    int*   nbr     = (int*)(attnT + (size_t)N_NODES * H_HEADS);   // N*MAXK
    int*   nbr_cnt = nbr + (size_t)N_NODES * MAXK;                // N

    scan_kernel<<<N_NODES, 256, 0, stream>>>(A, nbr, nbr_cnt);

    dim3 grid1(N_NODES / 64, H_HEADS * 2);
    proj_kernel<<<grid1, 256, 0, stream>>>(X, W1, W2, a_self, a_neigh,
                                           featsT, feats2T, attsT, attnT);

    agg2_kernel<<<N_NODES, 256, 0, stream>>>(nbr, nbr_cnt, featsT, feats2T,
                                             attsT, attnT, bias, out);
}

// Round 5
// 251.887 us; speedup vs baseline: 1.0888x; 1.0888x over previous
//
#include <hip/hip_runtime.h>
#include <hip/hip_bf16.h>

// GraphAttention2: N=6144, F=128, C=64, H=4. A ~1% sparse + self loops.
// R5: re-fuse scan+softmax+gather (cross-block phase overlap: A-stream on HBM
// overlaps gathers on L2/LIC); featsT stored bf16 -> gather bytes halved
// (375 -> 187 MB). fp32 accumulate; feats2/bias/att vectors stay fp32.

#define N_NODES 6144
#define F_DIM   128
#define C_DIM   64
#define H_HEADS 4
#define HC      (H_HEADS * C_DIM)   // 256
#define MAXK    256   // max degree ~100 over 6144 rows (p=0.01); big margin

typedef unsigned short u16;

// ---------------------------------------------------------------------------
// Kernel 1: per-head projections.
//   featsB  : bf16 [N][H][C]  (512 B per node)  -- gather operand
//   feats2T : fp32 [N][H][C]                    -- read-once residual
//   attsT/attnT : fp32 [N][H] (16 B per node)
// Grid: (N/64, H*2). Block 256, 64x64 tile, K=128 LDS-resident.
// ---------------------------------------------------------------------------
__global__ __launch_bounds__(256) void proj_kernel(
    const float* __restrict__ X,
    const float* __restrict__ W1, const float* __restrict__ W2,
    const float* __restrict__ a_self, const float* __restrict__ a_neigh,
    u16* __restrict__ featsB, float* __restrict__ feats2T,
    float* __restrict__ attsT, float* __restrict__ attnT)
{
    const int rt    = blockIdx.x;
    const int z     = blockIdx.y;
    const int h     = z >> 1;
    const int which = z & 1;

    const float* W = (which ? W2 : W1) + h * F_DIM * C_DIM;

    __shared__ float  Xs[64][132];    // [r][k], +4 pad
    __shared__ float4 Ws4[128][17];   // [k][c/4], +1 float4 pad

    const int tid = threadIdx.x;

    {
        const float4* Xg = (const float4*)(X + (size_t)rt * 64 * F_DIM);
        for (int u = tid; u < 64 * 32; u += 256) {
            const int r = u >> 5, q = u & 31;
            *(float4*)&Xs[r][4 * q] = Xg[u];
        }
        const float4* Wg = (const float4*)W;
        for (int u = tid; u < 128 * 16; u += 256) {
            Ws4[u >> 4][u & 15] = Wg[u];
        }
    }
    __syncthreads();

    const int tx = tid & 15;   // cols 4*tx..4*tx+3
    const int ty = tid >> 4;   // rows 4*ty..4*ty+3

    float acc[4][4] = {};
    for (int k = 0; k < 128; k += 4) {
        const float4 b0 = Ws4[k + 0][tx];
        const float4 b1 = Ws4[k + 1][tx];
        const float4 b2 = Ws4[k + 2][tx];
        const float4 b3 = Ws4[k + 3][tx];
        #pragma unroll
        for (int i = 0; i < 4; ++i) {
            const float4 x = *(const float4*)&Xs[4 * ty + i][k];
            acc[i][0] += x.x * b0.x + x.y * b1.x + x.z * b2.x + x.w * b3.x;
            acc[i][1] += x.x * b0.y + x.y * b1.y + x.z * b2.y + x.w * b3.y;
            acc[i][2] += x.x * b0.z + x.y * b1.z + x.z * b2.z + x.w * b3.z;
            acc[i][3] += x.x * b0.w + x.y * b1.w + x.z * b2.w + x.w * b3.w;
        }
    }

    __syncthreads();           // Xs free; reuse as C-tile scratch
    float* Ct = &Xs[0][0];     // viewed as [64][65]

    #pragma unroll
    for (int i = 0; i < 4; ++i) {
        const int r    = 4 * ty + i;
        const int node = rt * 64 + r;
        if (which == 0) {
            // bf16 pack (RNE via __float2bfloat16), 8 B store
            u16 p0 = __bfloat16_as_ushort(__float2bfloat16(acc[i][0]));
            u16 p1 = __bfloat16_as_ushort(__float2bfloat16(acc[i][1]));
            u16 p2 = __bfloat16_as_ushort(__float2bfloat16(acc[i][2]));
            u16 p3 = __bfloat16_as_ushort(__float2bfloat16(acc[i][3]));
            ushort4 pk; pk.x = p0; pk.y = p1; pk.z = p2; pk.w = p3;
            *(ushort4*)&featsB[(size_t)node * HC + h * C_DIM + 4 * tx] = pk;
            Ct[r * 65 + 4 * tx + 0] = acc[i][0];
            Ct[r * 65 + 4 * tx + 1] = acc[i][1];
            Ct[r * 65 + 4 * tx + 2] = acc[i][2];
            Ct[r * 65 + 4 * tx + 3] = acc[i][3];
        } else {
            *(float4*)&feats2T[(size_t)node * HC + h * C_DIM + 4 * tx] =
                make_float4(acc[i][0], acc[i][1], acc[i][2], acc[i][3]);
        }
    }

    if (which == 0) {
        __syncthreads();
        if (tid < 64) {
            const float* as_ = a_self  + h * C_DIM;
            const float* an_ = a_neigh + h * C_DIM;
            float s = 0.f, n = 0.f;
            #pragma unroll 8
            for (int c = 0; c < C_DIM; ++c) {
                const float v = Ct[tid * 65 + c];
                s += v * as_[c];
                n += v * an_[c];
            }
            const int node = rt * 64 + tid;
            attsT[node * H_HEADS + h] = s;
            attnT[node * H_HEADS + h] = n;
        }
    }
}

// ---------------------------------------------------------------------------
// Kernel 2 (fused): A-row scan + per-head softmax + bf16 gather-aggregate.
// One block (256) per node. Cross-block overlap: some blocks stream A (HBM)
// while others gather (L2/LIC) -- both pipes stay busy.
// ---------------------------------------------------------------------------
__global__ __launch_bounds__(256) void agg_kernel(
    const float* __restrict__ A,
    const u16* __restrict__ featsB, const float* __restrict__ feats2T,
    const float* __restrict__ attsT, const float* __restrict__ attnT,
    const float* __restrict__ bias,
    float* __restrict__ out)
{
    const int i   = blockIdx.x;
    const int tid = threadIdx.x;

    __shared__ int   idxs[MAXK];
    __shared__ float ews[H_HEADS][MAXK];
    __shared__ int   cnt;
    __shared__ float mh[H_HEADS], Zh[H_HEADS], si[H_HEADS];
    __shared__ float nodebuf[256];

    if (tid == 0) cnt = 0;
    if (tid < H_HEADS) si[tid] = attsT[i * H_HEADS + tid];
    __syncthreads();

    // Phase A: 6 upfront float4 loads per lane (96 B in flight), then compact.
    const float4* Arow = (const float4*)(A + (size_t)i * N_NODES);
    const float4 v0 = Arow[tid];
    const float4 v1 = Arow[tid + 256];
    const float4 v2 = Arow[tid + 512];
    const float4 v3 = Arow[tid + 768];
    const float4 v4 = Arow[tid + 1024];
    const float4 v5 = Arow[tid + 1280];

    #define SCAN4(v, base)                                                                    \
        if ((v).x > 0.5f) { int p = atomicAdd(&cnt, 1); if (p < MAXK) idxs[p] = (base) + 0; } \
        if ((v).y > 0.5f) { int p = atomicAdd(&cnt, 1); if (p < MAXK) idxs[p] = (base) + 1; } \
        if ((v).z > 0.5f) { int p = atomicAdd(&cnt, 1); if (p < MAXK) idxs[p] = (base) + 2; } \
        if ((v).w > 0.5f) { int p = atomicAdd(&cnt, 1); if (p < MAXK) idxs[p] = (base) + 3; }
    SCAN4(v0, 4 * tid)
    SCAN4(v1, 4 * (tid + 256))
    SCAN4(v2, 4 * (tid + 512))
    SCAN4(v3, 4 * (tid + 768))
    SCAN4(v4, 4 * (tid + 1024))
    SCAN4(v5, 4 * (tid + 1280))
    #undef SCAN4
    __syncthreads();
    const int K = min(cnt, MAXK);

    // Phase B1: logits (one float4 attnT load gives all 4 heads)
    const float4* an4 = (const float4*)attnT;
    for (int k = tid; k < K; k += 256) {
        const float4 an = an4[idxs[k]];
        float l;
        l = si[0] + an.x; ews[0][k] = (l > 0.f) ? l : 0.2f * l;
        l = si[1] + an.y; ews[1][k] = (l > 0.f) ? l : 0.2f * l;
        l = si[2] + an.z; ews[2][k] = (l > 0.f) ? l : 0.2f * l;
        l = si[3] + an.w; ews[3][k] = (l > 0.f) ? l : 0.2f * l;
    }
    __syncthreads();

    const int w    = tid >> 6;   // wave id == head id
    const int lane = tid & 63;

    // Phase B2: per-head max
    {
        float m = -1e30f;
        for (int k = lane; k < K; k += 64) m = fmaxf(m, ews[w][k]);
        #pragma unroll
        for (int off = 32; off > 0; off >>= 1) m = fmaxf(m, __shfl_down(m, off));
        if (lane == 0) mh[w] = m;
    }
    __syncthreads();

    // Phase B3: exp + per-head sum
    {
        const float m = mh[w];
        float zsum = 0.f;
        for (int k = lane; k < K; k += 64) {
            const float e = __expf(ews[w][k] - m);
            ews[w][k] = e;
            zsum += e;
        }
        #pragma unroll
        for (int off = 32; off > 0; off >>= 1) zsum += __shfl_down(zsum, off);
        if (lane == 0) Zh[w] = zsum;
    }
    __syncthreads();

    // Phase C: bf16 gather-accumulate, 8 independent loads in flight.
    // Wave w = head h, lane = channel c; each wave-load = 128 B (2 lines).
    const int h = w, c = lane;
    const u16* fh = featsB + h * C_DIM + c;   // stride HC=256 per node
    float acc = 0.f;
    int k = 0;
    for (; k + 8 <= K; k += 8) {
        const int4   j0 = *(const int4*)&idxs[k];
        const int4   j1 = *(const int4*)&idxs[k + 4];
        const float4 w0 = *(const float4*)&ews[h][k];
        const float4 w1 = *(const float4*)&ews[h][k + 4];
        const u16 r0 = fh[(size_t)j0.x * HC];
        const u16 r1 = fh[(size_t)j0.y * HC];
        const u16 r2 = fh[(size_t)j0.z * HC];
        const u16 r3 = fh[(size_t)j0.w * HC];
        const u16 r4 = fh[(size_t)j1.x * HC];
        const u16 r5 = fh[(size_t)j1.y * HC];
        const u16 r6 = fh[(size_t)j1.z * HC];
        const u16 r7 = fh[(size_t)j1.w * HC];
        acc += w0.x * __bfloat162float(__ushort_as_bfloat16(r0))
             + w0.y * __bfloat162float(__ushort_as_bfloat16(r1))
             + w0.z * __bfloat162float(__ushort_as_bfloat16(r2))
             + w0.w * __bfloat162float(__ushort_as_bfloat16(r3))
             + w1.x * __bfloat162float(__ushort_as_bfloat16(r4))
             + w1.y * __bfloat162float(__ushort_as_bfloat16(r5))
             + w1.z * __bfloat162float(__ushort_as_bfloat16(r6))
             + w1.w * __bfloat162float(__ushort_as_bfloat16(r7));
    }
    for (; k < K; ++k)
        acc += ews[h][k] * __bfloat162float(__ushort_as_bfloat16(fh[(size_t)idxs[k] * HC]));

    const float node = acc / Zh[h]
                     + feats2T[(size_t)i * HC + tid]
                     + bias[tid];                 // bias[h][c] == bias[tid]
    nodebuf[tid] = node;
    __syncthreads();

    // Phase D: head mean + relu
    if (tid < 64) {
        const float s = nodebuf[tid] + nodebuf[64 + tid] + nodebuf[128 + tid] + nodebuf[192 + tid];
        out[(size_t)i * C_DIM + tid] = fmaxf(0.25f * s, 0.f);
    }
}

extern "C" void kernel_launch(void* const* d_in, const int* in_sizes, int n_in,
                              void* d_out, int out_size, void* d_ws, size_t ws_size,
                              hipStream_t stream) {
    const float* X       = (const float*)d_in[0];
    const float* A       = (const float*)d_in[1];
    const float* W1      = (const float*)d_in[2];
    const float* W2      = (const float*)d_in[3];
    const float* a_self  = (const float*)d_in[4];
    const float* a_neigh = (const float*)d_in[5];
    const float* bias    = (const float*)d_in[6];
    float* out = (float*)d_out;

    // Workspace: feats2T fp32 | attsT | attnT | featsB bf16 (~9.6 MB total)
    float* ws      = (float*)d_ws;
    float* feats2T = ws;                                    // N*HC fp32
    float* attsT   = feats2T + (size_t)N_NODES * HC;        // N*H
    float* attnT   = attsT   + (size_t)N_NODES * H_HEADS;
    u16*   featsB  = (u16*)(attnT + (size_t)N_NODES * H_HEADS);  // N*HC bf16

    dim3 grid1(N_NODES / 64, H_HEADS * 2);
    proj_kernel<<<grid1, 256, 0, stream>>>(X, W1, W2, a_self, a_neigh,
                                           featsB, feats2T, attsT, attnT);

    agg_kernel<<<N_NODES, 256, 0, stream>>>(A, featsB, feats2T, attsT, attnT, bias, out);
}

// Round 6
// 250.394 us; speedup vs baseline: 1.0953x; 1.0060x over previous
//
#include <hip/hip_runtime.h>
#include <hip/hip_bf16.h>

// GraphAttention2: N=6144, F=128, C=64, H=4. A ~1% sparse + self loops.
// R6: non-temporal loads for the 151 MB A-stream (and read-once feats2T) so
// the bf16 gather operand featsB (3.1 MB) stays resident in per-XCD L2
// instead of being evicted to LIC. Also drops the softmax max-pass (logits
// bounded, exp(l)/sum(exp(l)) == softmax in fp32 range).

#define N_NODES 6144
#define F_DIM   128
#define C_DIM   64
#define H_HEADS 4
#define HC      (H_HEADS * C_DIM)   // 256
#define MAXK    256   // max degree ~100 over 6144 rows (p=0.01); big margin

typedef unsigned short u16;
typedef float v4f __attribute__((ext_vector_type(4)));

// ---------------------------------------------------------------------------
// Kernel 1: per-head projections.
//   featsB  : bf16 [N][H][C]  (512 B per node)  -- gather operand (L2-resident)
//   feats2T : fp32 [N][H][C]                    -- read-once residual
//   attsT/attnT : fp32 [N][H] (16 B per node)
// Grid: (N/64, H*2). Block 256, 64x64 tile, K=128 LDS-resident.
// ---------------------------------------------------------------------------
__global__ __launch_bounds__(256) void proj_kernel(
    const float* __restrict__ X,
    const float* __restrict__ W1, const float* __restrict__ W2,
    const float* __restrict__ a_self, const float* __restrict__ a_neigh,
    u16* __restrict__ featsB, float* __restrict__ feats2T,
    float* __restrict__ attsT, float* __restrict__ attnT)
{
    const int rt    = blockIdx.x;
    const int z     = blockIdx.y;
    const int h     = z >> 1;
    const int which = z & 1;

    const float* W = (which ? W2 : W1) + h * F_DIM * C_DIM;

    __shared__ float  Xs[64][132];    // [r][k], +4 pad
    __shared__ float4 Ws4[128][17];   // [k][c/4], +1 float4 pad

    const int tid = threadIdx.x;

    {
        const float4* Xg = (const float4*)(X + (size_t)rt * 64 * F_DIM);
        for (int u = tid; u < 64 * 32; u += 256) {
            const int r = u >> 5, q = u & 31;
            *(float4*)&Xs[r][4 * q] = Xg[u];
        }
        const float4* Wg = (const float4*)W;
        for (int u = tid; u < 128 * 16; u += 256) {
            Ws4[u >> 4][u & 15] = Wg[u];
        }
    }
    __syncthreads();

    const int tx = tid & 15;   // cols 4*tx..4*tx+3
    const int ty = tid >> 4;   // rows 4*ty..4*ty+3

    float acc[4][4] = {};
    for (int k = 0; k < 128; k += 4) {
        const float4 b0 = Ws4[k + 0][tx];
        const float4 b1 = Ws4[k + 1][tx];
        const float4 b2 = Ws4[k + 2][tx];
        const float4 b3 = Ws4[k + 3][tx];
        #pragma unroll
        for (int i = 0; i < 4; ++i) {
            const float4 x = *(const float4*)&Xs[4 * ty + i][k];
            acc[i][0] += x.x * b0.x + x.y * b1.x + x.z * b2.x + x.w * b3.x;
            acc[i][1] += x.x * b0.y + x.y * b1.y + x.z * b2.y + x.w * b3.y;
            acc[i][2] += x.x * b0.z + x.y * b1.z + x.z * b2.z + x.w * b3.z;
            acc[i][3] += x.x * b0.w + x.y * b1.w + x.z * b2.w + x.w * b3.w;
        }
    }

    __syncthreads();           // Xs free; reuse as C-tile scratch
    float* Ct = &Xs[0][0];     // viewed as [64][65]

    #pragma unroll
    for (int i = 0; i < 4; ++i) {
        const int r    = 4 * ty + i;
        const int node = rt * 64 + r;
        if (which == 0) {
            u16 p0 = __bfloat16_as_ushort(__float2bfloat16(acc[i][0]));
            u16 p1 = __bfloat16_as_ushort(__float2bfloat16(acc[i][1]));
            u16 p2 = __bfloat16_as_ushort(__float2bfloat16(acc[i][2]));
            u16 p3 = __bfloat16_as_ushort(__float2bfloat16(acc[i][3]));
            ushort4 pk; pk.x = p0; pk.y = p1; pk.z = p2; pk.w = p3;
            *(ushort4*)&featsB[(size_t)node * HC + h * C_DIM + 4 * tx] = pk;
            Ct[r * 65 + 4 * tx + 0] = acc[i][0];
            Ct[r * 65 + 4 * tx + 1] = acc[i][1];
            Ct[r * 65 + 4 * tx + 2] = acc[i][2];
            Ct[r * 65 + 4 * tx + 3] = acc[i][3];
        } else {
            *(float4*)&feats2T[(size_t)node * HC + h * C_DIM + 4 * tx] =
                make_float4(acc[i][0], acc[i][1], acc[i][2], acc[i][3]);
        }
    }

    if (which == 0) {
        __syncthreads();
        if (tid < 64) {
            const float* as_ = a_self  + h * C_DIM;
            const float* an_ = a_neigh + h * C_DIM;
            float s = 0.f, n = 0.f;
            #pragma unroll 8
            for (int c = 0; c < C_DIM; ++c) {
                const float v = Ct[tid * 65 + c];
                s += v * as_[c];
                n += v * an_[c];
            }
            const int node = rt * 64 + tid;
            attsT[node * H_HEADS + h] = s;
            attnT[node * H_HEADS + h] = n;
        }
    }
}

// ---------------------------------------------------------------------------
// Kernel 2 (fused): nt A-row scan + per-head softmax + bf16 gather-aggregate.
// One block (256) per node. nt loads keep featsB L2-resident.
// ---------------------------------------------------------------------------
__global__ __launch_bounds__(256) void agg_kernel(
    const float* __restrict__ A,
    const u16* __restrict__ featsB, const float* __restrict__ feats2T,
    const float* __restrict__ attsT, const float* __restrict__ attnT,
    const float* __restrict__ bias,
    float* __restrict__ out)
{
    const int i   = blockIdx.x;
    const int tid = threadIdx.x;

    __shared__ int   idxs[MAXK];
    __shared__ float ews[H_HEADS][MAXK];
    __shared__ int   cnt;
    __shared__ float Zh[H_HEADS], si[H_HEADS];
    __shared__ float nodebuf[256];

    if (tid == 0) cnt = 0;
    if (tid < H_HEADS) si[tid] = attsT[i * H_HEADS + tid];
    __syncthreads();

    // Phase A: 6 upfront NON-TEMPORAL float4 loads per lane (96 B in flight).
    // nt -> evict-first in L1/L2: the 151 MB stream doesn't displace featsB.
    const v4f* Arow = (const v4f*)(A + (size_t)i * N_NODES);
    const v4f v0 = __builtin_nontemporal_load(Arow + tid);
    const v4f v1 = __builtin_nontemporal_load(Arow + tid + 256);
    const v4f v2 = __builtin_nontemporal_load(Arow + tid + 512);
    const v4f v3 = __builtin_nontemporal_load(Arow + tid + 768);
    const v4f v4 = __builtin_nontemporal_load(Arow + tid + 1024);
    const v4f v5 = __builtin_nontemporal_load(Arow + tid + 1280);

    #define SCAN4(v, base)                                                                    \
        if ((v).x > 0.5f) { int p = atomicAdd(&cnt, 1); if (p < MAXK) idxs[p] = (base) + 0; } \
        if ((v).y > 0.5f) { int p = atomicAdd(&cnt, 1); if (p < MAXK) idxs[p] = (base) + 1; } \
        if ((v).z > 0.5f) { int p = atomicAdd(&cnt, 1); if (p < MAXK) idxs[p] = (base) + 2; } \
        if ((v).w > 0.5f) { int p = atomicAdd(&cnt, 1); if (p < MAXK) idxs[p] = (base) + 3; }
    SCAN4(v0, 4 * tid)
    SCAN4(v1, 4 * (tid + 256))
    SCAN4(v2, 4 * (tid + 512))
    SCAN4(v3, 4 * (tid + 768))
    SCAN4(v4, 4 * (tid + 1024))
    SCAN4(v5, 4 * (tid + 1280))
    #undef SCAN4
    __syncthreads();
    const int K = min(cnt, MAXK);

    // Phase B1: exp(leaky(logit)) directly -- no max pass. |logit| <~ 12 so
    // exp() is safely inside fp32 range; exp(l)/sum == softmax exactly.
    const float4* an4 = (const float4*)attnT;
    for (int k = tid; k < K; k += 256) {
        const float4 an = an4[idxs[k]];
        float l;
        l = si[0] + an.x; ews[0][k] = __expf((l > 0.f) ? l : 0.2f * l);
        l = si[1] + an.y; ews[1][k] = __expf((l > 0.f) ? l : 0.2f * l);
        l = si[2] + an.z; ews[2][k] = __expf((l > 0.f) ? l : 0.2f * l);
        l = si[3] + an.w; ews[3][k] = __expf((l > 0.f) ? l : 0.2f * l);
    }
    __syncthreads();

    const int w    = tid >> 6;   // wave id == head id
    const int lane = tid & 63;

    // Phase B2: per-head sum
    {
        float zsum = 0.f;
        for (int k = lane; k < K; k += 64) zsum += ews[w][k];
        #pragma unroll
        for (int off = 32; off > 0; off >>= 1) zsum += __shfl_down(zsum, off);
        if (lane == 0) Zh[w] = zsum;
    }
    __syncthreads();

    // Phase C: bf16 gather-accumulate, 8 independent loads in flight.
    // Wave w = head h, lane = channel c; each wave-load = 128 B contiguous.
    const int h = w, c = lane;
    const u16* fh = featsB + h * C_DIM + c;   // stride HC=256 per node
    float acc = 0.f;
    int k = 0;
    for (; k + 8 <= K; k += 8) {
        const int4   j0 = *(const int4*)&idxs[k];
        const int4   j1 = *(const int4*)&idxs[k + 4];
        const float4 w0 = *(const float4*)&ews[h][k];
        const float4 w1 = *(const float4*)&ews[h][k + 4];
        const u16 r0 = fh[(size_t)j0.x * HC];
        const u16 r1 = fh[(size_t)j0.y * HC];
        const u16 r2 = fh[(size_t)j0.z * HC];
        const u16 r3 = fh[(size_t)j0.w * HC];
        const u16 r4 = fh[(size_t)j1.x * HC];
        const u16 r5 = fh[(size_t)j1.y * HC];
        const u16 r6 = fh[(size_t)j1.z * HC];
        const u16 r7 = fh[(size_t)j1.w * HC];
        acc += w0.x * __bfloat162float(__ushort_as_bfloat16(r0))
             + w0.y * __bfloat162float(__ushort_as_bfloat16(r1))
             + w0.z * __bfloat162float(__ushort_as_bfloat16(r2))
             + w0.w * __bfloat162float(__ushort_as_bfloat16(r3))
             + w1.x * __bfloat162float(__ushort_as_bfloat16(r4))
             + w1.y * __bfloat162float(__ushort_as_bfloat16(r5))
             + w1.z * __bfloat162float(__ushort_as_bfloat16(r6))
             + w1.w * __bfloat162float(__ushort_as_bfloat16(r7));
    }
    for (; k < K; ++k)
        acc += ews[h][k] * __bfloat162float(__ushort_as_bfloat16(fh[(size_t)idxs[k] * HC]));

    // feats2T is read exactly once -> non-temporal.
    const float f2 = __builtin_nontemporal_load(&feats2T[(size_t)i * HC + tid]);
    const float node = acc / Zh[h] + f2 + bias[tid];   // bias[h][c] == bias[tid]
    nodebuf[tid] = node;
    __syncthreads();

    // Phase D: head mean + relu
    if (tid < 64) {
        const float s = nodebuf[tid] + nodebuf[64 + tid] + nodebuf[128 + tid] + nodebuf[192 + tid];
        out[(size_t)i * C_DIM + tid] = fmaxf(0.25f * s, 0.f);
    }
}

extern "C" void kernel_launch(void* const* d_in, const int* in_sizes, int n_in,
                              void* d_out, int out_size, void* d_ws, size_t ws_size,
                              hipStream_t stream) {
    const float* X       = (const float*)d_in[0];
    const float* A       = (const float*)d_in[1];
    const float* W1      = (const float*)d_in[2];
    const float* W2      = (const float*)d_in[3];
    const float* a_self  = (const float*)d_in[4];
    const float* a_neigh = (const float*)d_in[5];
    const float* bias    = (const float*)d_in[6];
    float* out = (float*)d_out;

    // Workspace: feats2T fp32 | attsT | attnT | featsB bf16 (~9.6 MB total)
    float* ws      = (float*)d_ws;
    float* feats2T = ws;                                    // N*HC fp32
    float* attsT   = feats2T + (size_t)N_NODES * HC;        // N*H
    float* attnT   = attsT   + (size_t)N_NODES * H_HEADS;
    u16*   featsB  = (u16*)(attnT + (size_t)N_NODES * H_HEADS);  // N*HC bf16

    dim3 grid1(N_NODES / 64, H_HEADS * 2);
    proj_kernel<<<grid1, 256, 0, stream>>>(X, W1, W2, a_self, a_neigh,
                                           featsB, feats2T, attsT, attnT);

    agg_kernel<<<N_NODES, 256, 0, stream>>>(A, featsB, feats2T, attsT, attnT, bias, out);
}

// Round 7
// 244.370 us; speedup vs baseline: 1.1223x; 1.0247x over previous
//
#include <hip/hip_runtime.h>
#include <hip/hip_bf16.h>

// GraphAttention2: N=6144, F=128, C=64, H=4. A ~1% sparse + self loops.
// R7: wave-per-row barrier-free aggregation. One wave owns one row:
// ballot-compaction scan (no LDS atomics, no __syncthreads), register
// softmax, and full-node 512B gathers (one uint2/lane load covers all 4
// heads). Waves drift: A-stream (HBM) overlaps gathers (L2) naturally.

#define N_NODES 6144
#define F_DIM   128
#define C_DIM   64
#define H_HEADS 4
#define HC      (H_HEADS * C_DIM)   // 256
#define MAXKW   128   // per-row neighbor cap; max degree ~96 (p=0.01), P(>=128)~1e-7

typedef unsigned short u16;
typedef float v4f __attribute__((ext_vector_type(4)));

// ---------------------------------------------------------------------------
// Kernel 1: per-head projections (unchanged from R6).
//   featsB  : bf16 [N][H][C]  (512 B per node)  -- gather operand
//   feats2T : fp32 [N][H][C]                    -- read-once residual
//   attsT/attnT : fp32 [N][H] (16 B per node)
// ---------------------------------------------------------------------------
__global__ __launch_bounds__(256) void proj_kernel(
    const float* __restrict__ X,
    const float* __restrict__ W1, const float* __restrict__ W2,
    const float* __restrict__ a_self, const float* __restrict__ a_neigh,
    u16* __restrict__ featsB, float* __restrict__ feats2T,
    float* __restrict__ attsT, float* __restrict__ attnT)
{
    const int rt    = blockIdx.x;
    const int z     = blockIdx.y;
    const int h     = z >> 1;
    const int which = z & 1;

    const float* W = (which ? W2 : W1) + h * F_DIM * C_DIM;

    __shared__ float  Xs[64][132];    // [r][k], +4 pad
    __shared__ float4 Ws4[128][17];   // [k][c/4], +1 float4 pad

    const int tid = threadIdx.x;

    {
        const float4* Xg = (const float4*)(X + (size_t)rt * 64 * F_DIM);
        for (int u = tid; u < 64 * 32; u += 256) {
            const int r = u >> 5, q = u & 31;
            *(float4*)&Xs[r][4 * q] = Xg[u];
        }
        const float4* Wg = (const float4*)W;
        for (int u = tid; u < 128 * 16; u += 256) {
            Ws4[u >> 4][u & 15] = Wg[u];
        }
    }
    __syncthreads();

    const int tx = tid & 15;   // cols 4*tx..4*tx+3
    const int ty = tid >> 4;   // rows 4*ty..4*ty+3

    float acc[4][4] = {};
    for (int k = 0; k < 128; k += 4) {
        const float4 b0 = Ws4[k + 0][tx];
        const float4 b1 = Ws4[k + 1][tx];
        const float4 b2 = Ws4[k + 2][tx];
        const float4 b3 = Ws4[k + 3][tx];
        #pragma unroll
        for (int i = 0; i < 4; ++i) {
            const float4 x = *(const float4*)&Xs[4 * ty + i][k];
            acc[i][0] += x.x * b0.x + x.y * b1.x + x.z * b2.x + x.w * b3.x;
            acc[i][1] += x.x * b0.y + x.y * b1.y + x.z * b2.y + x.w * b3.y;
            acc[i][2] += x.x * b0.z + x.y * b1.z + x.z * b2.z + x.w * b3.z;
            acc[i][3] += x.x * b0.w + x.y * b1.w + x.z * b2.w + x.w * b3.w;
        }
    }

    __syncthreads();           // Xs free; reuse as C-tile scratch
    float* Ct = &Xs[0][0];     // viewed as [64][65]

    #pragma unroll
    for (int i = 0; i < 4; ++i) {
        const int r    = 4 * ty + i;
        const int node = rt * 64 + r;
        if (which == 0) {
            u16 p0 = __bfloat16_as_ushort(__float2bfloat16(acc[i][0]));
            u16 p1 = __bfloat16_as_ushort(__float2bfloat16(acc[i][1]));
            u16 p2 = __bfloat16_as_ushort(__float2bfloat16(acc[i][2]));
            u16 p3 = __bfloat16_as_ushort(__float2bfloat16(acc[i][3]));
            ushort4 pk; pk.x = p0; pk.y = p1; pk.z = p2; pk.w = p3;
            *(ushort4*)&featsB[(size_t)node * HC + h * C_DIM + 4 * tx] = pk;
            Ct[r * 65 + 4 * tx + 0] = acc[i][0];
            Ct[r * 65 + 4 * tx + 1] = acc[i][1];
            Ct[r * 65 + 4 * tx + 2] = acc[i][2];
            Ct[r * 65 + 4 * tx + 3] = acc[i][3];
        } else {
            *(float4*)&feats2T[(size_t)node * HC + h * C_DIM + 4 * tx] =
                make_float4(acc[i][0], acc[i][1], acc[i][2], acc[i][3]);
        }
    }

    if (which == 0) {
        __syncthreads();
        if (tid < 64) {
            const float* as_ = a_self  + h * C_DIM;
            const float* an_ = a_neigh + h * C_DIM;
            float s = 0.f, n = 0.f;
            #pragma unroll 8
            for (int c = 0; c < C_DIM; ++c) {
                const float v = Ct[tid * 65 + c];
                s += v * as_[c];
                n += v * an_[c];
            }
            const int node = rt * 64 + tid;
            attsT[node * H_HEADS + h] = s;
            attnT[node * H_HEADS + h] = n;
        }
    }
}

// ---------------------------------------------------------------------------
// Kernel 2: wave-per-row scan + softmax + gather. Block = 4 waves = 4 rows.
// Grid = N/4 = 1536. NO __syncthreads -- waves fully independent.
// ---------------------------------------------------------------------------
__global__ __launch_bounds__(256) void agg_kernel(
    const float* __restrict__ A,
    const u16* __restrict__ featsB, const float* __restrict__ feats2T,
    const float* __restrict__ attsT, const float* __restrict__ attnT,
    const float* __restrict__ bias,
    float* __restrict__ out)
{
    const int w    = threadIdx.x >> 6;   // wave id 0..3
    const int lane = threadIdx.x & 63;
    const int i    = blockIdx.x * 4 + w; // this wave's row

    __shared__ int    idxs[4][MAXKW];    // per-wave neighbor lists (2 KB)
    __shared__ float4 ewsT4[4][MAXKW];   // per-wave exp weights [k] (8 KB)
    int*    idx_w = idxs[w];
    float4* ews_w = ewsT4[w];

    // ---- Phase A: scan row i, ballot compaction (wave-uniform base).
    const v4f* Arow = (const v4f*)(A + (size_t)i * N_NODES);
    const unsigned long long ltmask = (1ull << lane) - 1ull;
    int base = 0;
    #pragma unroll
    for (int ch = 0; ch < 4; ++ch) {     // 4 chunks x 6 groups x 64 lanes x float4
        v4f v[6];
        #pragma unroll
        for (int g = 0; g < 6; ++g)
            v[g] = __builtin_nontemporal_load(Arow + lane + 64 * (ch * 6 + g));
        #pragma unroll
        for (int g = 0; g < 6; ++g) {
            const int col = 4 * (lane + 64 * (ch * 6 + g));
            #pragma unroll
            for (int m = 0; m < 4; ++m) {
                const float x = (m == 0) ? v[g].x : (m == 1) ? v[g].y
                              : (m == 2) ? v[g].z : v[g].w;
                const bool p = (x > 0.5f);
                const unsigned long long mask = __ballot(p);
                if (p) {
                    const int pos = base + (int)__popcll(mask & ltmask);
                    if (pos < MAXKW) idx_w[pos] = col + m;
                }
                base += (int)__popcll(mask);
            }
        }
    }
    const int K = min(base, MAXKW);

    // ---- Phase B: exp(leaky(logit)) in registers; Z via butterfly.
    // No max-pass: |logit| small, exp safely in fp32; exp/sum == softmax.
    const float4 si4 = ((const float4*)attsT)[i];
    float zx = 0.f, zy = 0.f, zz = 0.f, zw = 0.f;
    #pragma unroll
    for (int r = 0; r < 2; ++r) {
        const int k = lane + 64 * r;
        if (k < K) {
            const float4 an = ((const float4*)attnT)[idx_w[k]];
            float l;
            float4 e4;
            l = si4.x + an.x; e4.x = __expf((l > 0.f) ? l : 0.2f * l);
            l = si4.y + an.y; e4.y = __expf((l > 0.f) ? l : 0.2f * l);
            l = si4.z + an.z; e4.z = __expf((l > 0.f) ? l : 0.2f * l);
            l = si4.w + an.w; e4.w = __expf((l > 0.f) ? l : 0.2f * l);
            ews_w[k] = e4;
            zx += e4.x; zy += e4.y; zz += e4.z; zw += e4.w;
        }
    }
    #pragma unroll
    for (int off = 32; off > 0; off >>= 1) {
        zx += __shfl_xor(zx, off);
        zy += __shfl_xor(zy, off);
        zz += __shfl_xor(zz, off);
        zw += __shfl_xor(zw, off);
    }
    const int hsel = lane >> 4;          // head owning channels 4*lane..4*lane+3
    const float zinv = 1.0f / ((hsel == 0) ? zx : (hsel == 1) ? zy
                             : (hsel == 2) ? zz : zw);

    // ---- Phase C: gather. Lane loads uint2 = 4 bf16 channels; one 512 B
    // wave-load covers the whole node (all heads). 8 loads in flight.
    const uint2* fb = (const uint2*)featsB;   // node j at fb[j*64 + lane]
    float a0 = 0.f, a1 = 0.f, a2 = 0.f, a3 = 0.f;

    #define UPFMA(q, wgt)                                                   \
        {                                                                   \
            const float f0 = __uint_as_float((q).x << 16);                  \
            const float f1 = __uint_as_float((q).x & 0xffff0000u);          \
            const float f2 = __uint_as_float((q).y << 16);                  \
            const float f3 = __uint_as_float((q).y & 0xffff0000u);          \
            a0 += (wgt) * f0; a1 += (wgt) * f1;                             \
            a2 += (wgt) * f2; a3 += (wgt) * f3;                             \
        }

    int k = 0;
    for (; k + 8 <= K; k += 8) {
        const int4 j0 = *(const int4*)&idx_w[k];      // LDS broadcast
        const int4 j1 = *(const int4*)&idx_w[k + 4];
        const float w0 = ((const float*)&ews_w[k + 0])[hsel];
        const float w1 = ((const float*)&ews_w[k + 1])[hsel];
        const float w2 = ((const float*)&ews_w[k + 2])[hsel];
        const float w3 = ((const float*)&ews_w[k + 3])[hsel];
        const float w4 = ((const float*)&ews_w[k + 4])[hsel];
        const float w5 = ((const float*)&ews_w[k + 5])[hsel];
        const float w6 = ((const float*)&ews_w[k + 6])[hsel];
        const float w7 = ((const float*)&ews_w[k + 7])[hsel];
        const uint2 q0 = fb[(size_t)j0.x * 64 + lane];
        const uint2 q1 = fb[(size_t)j0.y * 64 + lane];
        const uint2 q2 = fb[(size_t)j0.z * 64 + lane];
        const uint2 q3 = fb[(size_t)j0.w * 64 + lane];
        const uint2 q4 = fb[(size_t)j1.x * 64 + lane];
        const uint2 q5 = fb[(size_t)j1.y * 64 + lane];
        const uint2 q6 = fb[(size_t)j1.z * 64 + lane];
        const uint2 q7 = fb[(size_t)j1.w * 64 + lane];
        UPFMA(q0, w0) UPFMA(q1, w1) UPFMA(q2, w2) UPFMA(q3, w3)
        UPFMA(q4, w4) UPFMA(q5, w5) UPFMA(q6, w6) UPFMA(q7, w7)
    }
    for (; k < K; ++k) {
        const int   j  = idx_w[k];
        const float wg = ((const float*)&ews_w[k])[hsel];
        const uint2 q  = fb[(size_t)j * 64 + lane];
        UPFMA(q, wg)
    }
    #undef UPFMA

    // ---- Phase D: epilogue. normalize, +feats2+bias, head-mean, relu.
    const float4 f2 = *(const float4*)&feats2T[(size_t)i * HC + 4 * lane];
    const float4 b4 = *(const float4*)&bias[4 * lane];
    float s0 = a0 * zinv + f2.x + b4.x;
    float s1 = a1 * zinv + f2.y + b4.y;
    float s2 = a2 * zinv + f2.z + b4.z;
    float s3 = a3 * zinv + f2.w + b4.w;
    // sum over heads: lanes {l, l+16, l+32, l+48} hold same channels
    s0 += __shfl_xor(s0, 16); s0 += __shfl_xor(s0, 32);
    s1 += __shfl_xor(s1, 16); s1 += __shfl_xor(s1, 32);
    s2 += __shfl_xor(s2, 16); s2 += __shfl_xor(s2, 32);
    s3 += __shfl_xor(s3, 16); s3 += __shfl_xor(s3, 32);
    if (lane < 16) {
        float4 o;
        o.x = fmaxf(0.25f * s0, 0.f);
        o.y = fmaxf(0.25f * s1, 0.f);
        o.z = fmaxf(0.25f * s2, 0.f);
        o.w = fmaxf(0.25f * s3, 0.f);
        *(float4*)&out[(size_t)i * C_DIM + 4 * lane] = o;
    }
}

extern "C" void kernel_launch(void* const* d_in, const int* in_sizes, int n_in,
                              void* d_out, int out_size, void* d_ws, size_t ws_size,
                              hipStream_t stream) {
    const float* X       = (const float*)d_in[0];
    const float* A       = (const float*)d_in[1];
    const float* W1      = (const float*)d_in[2];
    const float* W2      = (const float*)d_in[3];
    const float* a_self  = (const float*)d_in[4];
    const float* a_neigh = (const float*)d_in[5];
    const float* bias    = (const float*)d_in[6];
    float* out = (float*)d_out;

    // Workspace: feats2T fp32 | attsT | attnT | featsB bf16 (~9.6 MB total)
    float* ws      = (float*)d_ws;
    float* feats2T = ws;                                    // N*HC fp32
    float* attsT   = feats2T + (size_t)N_NODES * HC;        // N*H
    float* attnT   = attsT   + (size_t)N_NODES * H_HEADS;
    u16*   featsB  = (u16*)(attnT + (size_t)N_NODES * H_HEADS);  // N*HC bf16

    dim3 grid1(N_NODES / 64, H_HEADS * 2);
    proj_kernel<<<grid1, 256, 0, stream>>>(X, W1, W2, a_self, a_neigh,
                                           featsB, feats2T, attsT, attnT);

    agg_kernel<<<N_NODES / 4, 256, 0, stream>>>(A, featsB, feats2T, attsT, attnT, bias, out);
}